// Round 1
// 1560.729 us; speedup vs baseline: 1.2779x; 1.2779x over previous
//
#include <hip/hip_runtime.h>
#include <hip/hip_bf16.h>

typedef _Float16 f16x8 __attribute__((ext_vector_type(8)));
typedef float f32x4 __attribute__((ext_vector_type(4)));

namespace {
constexpr int N_ = 100000;
constexpr int E_ = 400000;
constexpr int D_ = 256;
constexpr int L_ = 3;
constexpr int R_ = 4;
constexpr int G_ = 2000;
constexpr int NRXN_ = 10;
constexpr int CTXW = L_*D_ + D_ + L_*D_ + NRXN_;   // 1802
constexpr int GCTXW = L_*D_ + NRXN_;               // 778
constexpr int NKT = (R_+1)*D_/32;                  // 40 k-tiles of 32
constexpr int NR = N_*R_;                          // 400000 (dst,type) bins
constexpr int NB2 = (NR + 2047)/2048;              // 196 scan blocks
}

// ---------- small utility kernels ----------

__global__ void k_zero(int* __restrict__ p, int n) {
  int i = blockIdx.x*256 + threadIdx.x;
  if (i < n) p[i] = 0;
}

// sniff center_mask dtype: 0=int32, 1=float32, 2=byte(bool)
__global__ void k_detect(const unsigned char* __restrict__ cm, int* __restrict__ meta) {
  int tid = threadIdx.x;
  int ok_i = 1, ok_f = 1;
  for (int i = tid; i < 4096; i += 256) {
    unsigned b = cm[i];
    int m = i & 3;
    if (m == 0)      { if (b > 1) ok_i = 0; if (b != 0) ok_f = 0; }
    else if (m == 1) { if (b) { ok_i = 0; ok_f = 0; } }
    else if (m == 2) { if (b) ok_i = 0; if (b != 0 && b != 0x80) ok_f = 0; }
    else             { if (b) ok_i = 0; if (b != 0 && b != 0x3f) ok_f = 0; }
  }
  int all_i = __syncthreads_and(ok_i);
  int all_f = __syncthreads_and(ok_f);
  if (tid == 0) meta[0] = all_i ? 0 : (all_f ? 1 : 2);
}

// histogram over (dst*4 + type) bins
__global__ void k_hist2(const int* __restrict__ dst, const int* __restrict__ typ,
                        int* __restrict__ hist, int n) {
  int i = blockIdx.x*256 + threadIdx.x;
  if (i < n) atomicAdd(&hist[dst[i]*4 + typ[i]], 1);
}

__global__ void k_hist(const int* __restrict__ key, int* __restrict__ hist, int n) {
  int i = blockIdx.x*256 + threadIdx.x;
  if (i < n) atomicAdd(&hist[key[i]], 1);
}

// exclusive scan, 2048 elems per block (8 per thread)
__global__ void k_scan1(const int* __restrict__ h, int* __restrict__ out,
                        int* __restrict__ bsum, int n) {
  __shared__ int sh[256];
  int t = threadIdx.x;
  int base = blockIdx.x*2048 + t*8;
  int v[8]; int s = 0;
  #pragma unroll
  for (int j = 0; j < 8; ++j) { v[j] = (base+j < n) ? h[base+j] : 0; s += v[j]; }
  sh[t] = s; __syncthreads();
  for (int off = 1; off < 256; off <<= 1) {
    int x = (t >= off) ? sh[t-off] : 0;
    __syncthreads();
    sh[t] += x;
    __syncthreads();
  }
  int ex = sh[t] - s;
  #pragma unroll
  for (int j = 0; j < 8; ++j) { if (base+j < n) out[base+j] = ex; ex += v[j]; }
  if (t == 255) bsum[blockIdx.x] = sh[255];
}

__global__ void k_scan2(int* __restrict__ b, int nb) {
  __shared__ int sh[256];
  int t = threadIdx.x;
  int s = (t < nb) ? b[t] : 0;
  sh[t] = s; __syncthreads();
  for (int off = 1; off < 256; off <<= 1) {
    int x = (t >= off) ? sh[t-off] : 0;
    __syncthreads();
    sh[t] += x;
    __syncthreads();
  }
  if (t < nb) b[t] = sh[t] - s;
}

__global__ void k_scan3(int* __restrict__ eoff, const int* __restrict__ bsum,
                        int* __restrict__ cursor, int n, int total) {
  int i = blockIdx.x*256 + threadIdx.x;
  if (i < n) {
    int v = eoff[i] + bsum[i >> 11];
    eoff[i] = v;
    cursor[i] = v;
  }
  if (i == 0) eoff[n] = total;
}

// scatter src into CSR-by-(dst,type) order
__global__ void k_scatter2(const int* __restrict__ src, const int* __restrict__ dst,
                           const int* __restrict__ typ, int* __restrict__ cursor,
                           int* __restrict__ out, int n) {
  int i = blockIdx.x*256 + threadIdx.x;
  if (i < n) {
    int key = dst[i]*4 + typ[i];
    int p = atomicAdd(&cursor[key], 1);
    out[p] = src[i];
  }
}

__global__ void k_scan_small(const int* __restrict__ gh, int* __restrict__ goff, int g) {
  __shared__ int sh[256];
  int t = threadIdx.x;
  int v[8]; int s = 0;
  #pragma unroll
  for (int j = 0; j < 8; ++j) { int idx = t*8+j; v[j] = (idx < g) ? gh[idx] : 0; s += v[j]; }
  sh[t] = s; __syncthreads();
  for (int off = 1; off < 256; off <<= 1) {
    int x = (t >= off) ? sh[t-off] : 0;
    __syncthreads();
    sh[t] += x;
    __syncthreads();
  }
  int ex = sh[t] - s;
  #pragma unroll
  for (int j = 0; j < 8; ++j) { int idx = t*8+j; if (idx < g) goff[idx] = ex; ex += v[j]; }
  if (t == 255) goff[g] = sh[255];
}

// pack W into MFMA B-fragment layout: Bp[((l*NKT+kt)*16+ct)*64+lane][j] =
//   B[k = kt*32 + (lane>>4)*8 + j][col = ct*16 + (lane&15)]
__global__ void k_pack_w(const float* __restrict__ Wrel, const float* __restrict__ Wself,
                         f16x8* __restrict__ Bp) {
  int id = blockIdx.x*256 + threadIdx.x;
  if (id >= L_*NKT*16*64) return;
  int lane = id & 63; int rest = id >> 6;
  int ct = rest & 15; rest >>= 4;
  int kt = rest % NKT; int l = rest / NKT;
  int q = lane >> 4, ln = lane & 15;
  int col = ct*16 + ln;
  f16x8 o;
  #pragma unroll
  for (int j = 0; j < 8; ++j) {
    int k = kt*32 + q*8 + j;
    float v = (k < R_*D_) ? Wrel[((size_t)l*R_*D_ + k)*D_ + col]
                          : Wself[((size_t)l*D_ + (k - R_*D_))*D_ + col];
    o[j] = (_Float16)v;
  }
  Bp[id] = o;
}

// x0 = node_feature + mask*flag_W[1] + flag_b  (f16); also copy node_feature to out cols [768:1024)
__global__ void k_node_init(const float* __restrict__ nf, const float* __restrict__ fW,
                            const float* __restrict__ fb, const void* __restrict__ cm,
                            const int* __restrict__ meta, _Float16* __restrict__ xa,
                            float* __restrict__ out) {
  int n = blockIdx.x, c = threadIdx.x;
  float v = nf[(size_t)n*D_ + c];
  out[(size_t)n*CTXW + 768 + c] = v;
  int mode = meta[0];
  bool mk;
  if (mode == 0)      mk = ((const int*)cm)[n] != 0;
  else if (mode == 1) mk = ((const float*)cm)[n] != 0.f;
  else                mk = ((const unsigned char*)cm)[n] != 0;
  float x0 = v + (mk ? fW[D_ + c] : 0.f) + fb[c];
  xa[(size_t)n*D_ + c] = (_Float16)x0;
}

// ---------- fused RGCN layer ----------
// block = 256 thr (4 waves), M-tile = 32 nodes (N_ % 32 == 0, no bounds checks).
// Gather: wave w owns rows [w*8, w*8+8); 8 lanes per row, each lane a 32-elem k-chunk.
//   Per edge iteration the wave loads 8 full src rows COALESCED (128B per 8-lane group
//   per dwordx4). Accumulate in 32 f32 regs per lane (no LDS RMW chain).
// CSR-by-(dst,type): exact per-relation segments, no divergent type test.
// A staged to LDS as f16, XOR-swizzled granules, double-buffered -> 1 barrier/relation.
__global__ __launch_bounds__(256, 3)
void k_layer(const _Float16* __restrict__ xin, const f16x8* __restrict__ Bp,
             const float* __restrict__ bias, const int* __restrict__ eoff2,
             const int* __restrict__ es, float* __restrict__ outp,
             _Float16* __restrict__ xout) {
  __shared__ f16x8 As16[2][32*32];   // [buf][row*32 + swizzled granule], 32 KB
  const int tid = threadIdx.x;
  const int lane = tid & 63, wave = tid >> 6;
  const int q = lane >> 4, ln = lane & 15;
  const int m0 = blockIdx.x * 32;
  const int kch = lane & 7;          // k-chunk within row (32 f16 = 64 B)
  const int row = wave*8 + (lane >> 3);  // 0..31
  const int nd  = m0 + row;

  int oo[5];
  #pragma unroll
  for (int j = 0; j < 5; ++j) oo[j] = eoff2[nd*4 + j];
  const int degt = oo[4] - oo[0];
  const float invd = 1.0f / (float)(degt > 1 ? degt : 1);

  f32x4 acc[2][4];
  #pragma unroll
  for (int rt = 0; rt < 2; ++rt)
    #pragma unroll
    for (int cc = 0; cc < 4; ++cc)
      acc[rt][cc] = f32x4{0.f,0.f,0.f,0.f};

  // ---- self phase: A = xin rows directly (k in [1024,1280)) ----
  {
    const _Float16* r0 = xin + (size_t)(m0 + ln)*D_;
    const _Float16* r1 = xin + (size_t)(m0 + 16 + ln)*D_;
    #pragma unroll
    for (int kt = 0; kt < 8; ++kt) {
      f16x8 a0 = *(const f16x8*)(r0 + kt*32 + q*8);
      f16x8 a1 = *(const f16x8*)(r1 + kt*32 + q*8);
      f16x8 b[4];
      #pragma unroll
      for (int cc = 0; cc < 4; ++cc)
        b[cc] = Bp[(size_t)((32 + kt)*16 + wave*4 + cc)*64 + lane];
      #pragma unroll
      for (int cc = 0; cc < 4; ++cc) {
        acc[0][cc] = __builtin_amdgcn_mfma_f32_16x16x32_f16(a0, b[cc], acc[0][cc], 0,0,0);
        acc[1][cc] = __builtin_amdgcn_mfma_f32_16x16x32_f16(a1, b[cc], acc[1][cc], 0,0,0);
      }
    }
  }

  // ---- relation phases ----
  #pragma unroll
  for (int r = 0; r < R_; ++r) {
    // register gather for (row, relation r)
    f32x4 ax[8];
    #pragma unroll
    for (int i = 0; i < 8; ++i) ax[i] = f32x4{0.f,0.f,0.f,0.f};
    for (int e = oo[r]; e < oo[r+1]; ++e) {
      int src = es[e];   // same for the 8 lanes of this row -> broadcast + coalesced row read
      const f16x8* sp = (const f16x8*)(xin + (size_t)src*D_ + kch*32);
      f16x8 w0 = sp[0], w1 = sp[1], w2 = sp[2], w3 = sp[3];
      ax[0] += f32x4{(float)w0[0],(float)w0[1],(float)w0[2],(float)w0[3]};
      ax[1] += f32x4{(float)w0[4],(float)w0[5],(float)w0[6],(float)w0[7]};
      ax[2] += f32x4{(float)w1[0],(float)w1[1],(float)w1[2],(float)w1[3]};
      ax[3] += f32x4{(float)w1[4],(float)w1[5],(float)w1[6],(float)w1[7]};
      ax[4] += f32x4{(float)w2[0],(float)w2[1],(float)w2[2],(float)w2[3]};
      ax[5] += f32x4{(float)w2[4],(float)w2[5],(float)w2[6],(float)w2[7]};
      ax[6] += f32x4{(float)w3[0],(float)w3[1],(float)w3[2],(float)w3[3]};
      ax[7] += f32x4{(float)w3[4],(float)w3[5],(float)w3[6],(float)w3[7]};
    }
    // scale by 1/deg, convert to f16, write swizzled A tile
    f16x8* dstb = &As16[r & 1][row*32];
    #pragma unroll
    for (int i = 0; i < 4; ++i) {
      f32x4 lo = ax[2*i], hi = ax[2*i+1];
      f16x8 o;
      o[0] = (_Float16)(lo[0]*invd); o[1] = (_Float16)(lo[1]*invd);
      o[2] = (_Float16)(lo[2]*invd); o[3] = (_Float16)(lo[3]*invd);
      o[4] = (_Float16)(hi[0]*invd); o[5] = (_Float16)(hi[1]*invd);
      o[6] = (_Float16)(hi[2]*invd); o[7] = (_Float16)(hi[3]*invd);
      dstb[(kch*4 + i) ^ (row & 7)] = o;
    }
    __syncthreads();
    const f16x8* As = As16[r & 1];
    #pragma unroll
    for (int kt = 0; kt < 8; ++kt) {
      f16x8 a0 = As[(size_t)ln*32      + ((kt*4 + q) ^ (ln & 7))];
      f16x8 a1 = As[(size_t)(16+ln)*32 + ((kt*4 + q) ^ (ln & 7))];
      f16x8 b[4];
      #pragma unroll
      for (int cc = 0; cc < 4; ++cc)
        b[cc] = Bp[(size_t)((r*8 + kt)*16 + wave*4 + cc)*64 + lane];
      #pragma unroll
      for (int cc = 0; cc < 4; ++cc) {
        acc[0][cc] = __builtin_amdgcn_mfma_f32_16x16x32_f16(a0, b[cc], acc[0][cc], 0,0,0);
        acc[1][cc] = __builtin_amdgcn_mfma_f32_16x16x32_f16(a1, b[cc], acc[1][cc], 0,0,0);
      }
    }
    // next relation writes the other buffer; its barrier also fences these reads
  }

  // epilogue: +bias, relu, write strided fp32 to out, compact f16 to xout
  #pragma unroll
  for (int cc = 0; cc < 4; ++cc) {
    int col = (wave*4 + cc)*16 + ln;
    float bv = bias[col];
    #pragma unroll
    for (int rt = 0; rt < 2; ++rt) {
      #pragma unroll
      for (int i = 0; i < 4; ++i) {
        int rrow = m0 + rt*16 + q*4 + i;
        float v = acc[rt][cc][i] + bv;
        v = fmaxf(v, 0.f);
        outp[(size_t)rrow*CTXW + col] = v;
        if (xout) xout[(size_t)rrow*D_ + col] = (_Float16)v;
      }
    }
  }
}

// segment-mean over sorted batch; one block per graph
__global__ void k_pool(float* __restrict__ out, const int* __restrict__ goff,
                       const int* __restrict__ rxn) {
  int g = blockIdx.x, t = threadIdx.x;
  int s = goff[g], e = goff[g+1];
  int cnt = e - s;
  float inv = 1.0f / (float)(cnt > 1 ? cnt : 1);
  float a0 = 0.f, a1 = 0.f, a2 = 0.f;
  for (int nn = s; nn < e; ++nn) {
    size_t base = (size_t)nn*CTXW;
    a0 += out[base + t];
    a1 += out[base + 256 + t];
    a2 += out[base + 512 + t];
  }
  size_t gbase = (size_t)N_*CTXW + (size_t)g*GCTXW;
  out[gbase + t]       = a0*inv;
  out[gbase + 256 + t] = a1*inv;
  out[gbase + 512 + t] = a2*inv;
  if (t < NRXN_) out[gbase + 768 + t] = (rxn[g] == t) ? 1.f : 0.f;
}

// node_context cols [1024,1802) = graph_context[batch[n]]
__global__ void k_bcast(float* __restrict__ out, const int* __restrict__ batch) {
  int nn = blockIdx.x, t = threadIdx.x;
  size_t gbase = (size_t)N_*CTXW + (size_t)batch[nn]*GCTXW;
  size_t nb = (size_t)nn*CTXW + 1024;
  out[nb + t]       = out[gbase + t];
  out[nb + 256 + t] = out[gbase + 256 + t];
  out[nb + 512 + t] = out[gbase + 512 + t];
  if (t < GCTXW - 768) out[nb + 768 + t] = out[gbase + 768 + t];
}

extern "C" void kernel_launch(void* const* d_in, const int* in_sizes, int n_in,
                              void* d_out, int out_size, void* d_ws, size_t ws_size,
                              hipStream_t stream) {
  const float* node_feature = (const float*)d_in[0];
  const float* flag_W  = (const float*)d_in[1];
  const float* flag_b  = (const float*)d_in[2];
  const float* W_self  = (const float*)d_in[3];
  const float* b_self  = (const float*)d_in[4];
  const float* W_rel   = (const float*)d_in[5];
  const int* edge_src  = (const int*)d_in[6];
  const int* edge_dst  = (const int*)d_in[7];
  const int* edge_type = (const int*)d_in[8];
  const int* batch     = (const int*)d_in[9];
  const int* reaction  = (const int*)d_in[10];
  const void* cmask    = d_in[11];
  float* out = (float*)d_out;

  char* ws = (char*)d_ws;
  size_t off = 0;
  auto alloc = [&](size_t bytes) {
    void* p = ws + off;
    off = (off + bytes + 255) & ~(size_t)255;
    return p;
  };
  int* meta          = (int*)alloc(256);
  _Float16* xa       = (_Float16*)alloc((size_t)N_*D_*2);
  _Float16* xb       = (_Float16*)alloc((size_t)N_*D_*2);
  f16x8* Bp          = (f16x8*)alloc((size_t)L_*NKT*16*64*16);
  int* eoff2         = (int*)alloc((size_t)(NR+1)*4);
  int* cursor        = (int*)alloc((size_t)NR*4);
  int* ghist         = (int*)alloc((size_t)G_*4);
  int* goff          = (int*)alloc((size_t)(G_+1)*4);
  int* bsum          = (int*)alloc(1024);
  int* esorted       = (int*)alloc((size_t)E_*4);
  (void)in_sizes; (void)n_in; (void)out_size; (void)ws_size;

  k_detect<<<1, 256, 0, stream>>>((const unsigned char*)cmask, meta);
  k_zero<<<(NR+255)/256, 256, 0, stream>>>(cursor, NR);
  k_zero<<<(G_+255)/256, 256, 0, stream>>>(ghist, G_);
  k_hist2<<<(E_+255)/256, 256, 0, stream>>>(edge_dst, edge_type, cursor, E_);
  k_scan1<<<NB2, 256, 0, stream>>>(cursor, eoff2, bsum, NR);
  k_scan2<<<1, 256, 0, stream>>>(bsum, NB2);
  k_scan3<<<(NR+255)/256, 256, 0, stream>>>(eoff2, bsum, cursor, NR, E_);
  k_scatter2<<<(E_+255)/256, 256, 0, stream>>>(edge_src, edge_dst, edge_type, cursor, esorted, E_);
  k_hist<<<(N_+255)/256, 256, 0, stream>>>(batch, ghist, N_);
  k_scan_small<<<1, 256, 0, stream>>>(ghist, goff, G_);
  k_pack_w<<<(L_*NKT*16*64 + 255)/256, 256, 0, stream>>>(W_rel, W_self, Bp);
  k_node_init<<<N_, 256, 0, stream>>>(node_feature, flag_W, flag_b, cmask, meta, xa, out);

  const int nblk = N_ / 32;
  k_layer<<<nblk, 256, 0, stream>>>(xa, Bp,          b_self,       eoff2, esorted, out,       xb);
  k_layer<<<nblk, 256, 0, stream>>>(xb, Bp + 40960,  b_self + 256, eoff2, esorted, out + 256, xa);
  k_layer<<<nblk, 256, 0, stream>>>(xa, Bp + 81920,  b_self + 512, eoff2, esorted, out + 512, nullptr);

  k_pool<<<G_, 256, 0, stream>>>(out, goff, reaction);
  k_bcast<<<N_, 256, 0, stream>>>(out, batch);
}

// Round 2
// 1511.080 us; speedup vs baseline: 1.3199x; 1.0329x over previous
//
#include <hip/hip_runtime.h>
#include <hip/hip_bf16.h>

typedef _Float16 f16x8 __attribute__((ext_vector_type(8)));
typedef float f32x4 __attribute__((ext_vector_type(4)));

namespace {
constexpr int N_ = 100000;
constexpr int E_ = 400000;
constexpr int D_ = 256;
constexpr int L_ = 3;
constexpr int R_ = 4;
constexpr int G_ = 2000;
constexpr int NRXN_ = 10;
constexpr int CTXW = L_*D_ + D_ + L_*D_ + NRXN_;   // 1802
constexpr int GCTXW = L_*D_ + NRXN_;               // 778
constexpr int NKT = (R_+1)*D_/32;                  // 40 k-tiles of 32
constexpr int NR = N_*R_;                          // 400000 (dst,type) bins
constexpr int NB2 = (NR + 2047)/2048;              // 196 scan blocks
}

// ---------- small utility kernels ----------

__global__ void k_zero(int* __restrict__ p, int n) {
  int i = blockIdx.x*256 + threadIdx.x;
  if (i < n) p[i] = 0;
}

// sniff center_mask dtype: 0=int32, 1=float32, 2=byte(bool)
__global__ void k_detect(const unsigned char* __restrict__ cm, int* __restrict__ meta) {
  int tid = threadIdx.x;
  int ok_i = 1, ok_f = 1;
  for (int i = tid; i < 4096; i += 256) {
    unsigned b = cm[i];
    int m = i & 3;
    if (m == 0)      { if (b > 1) ok_i = 0; if (b != 0) ok_f = 0; }
    else if (m == 1) { if (b) { ok_i = 0; ok_f = 0; } }
    else if (m == 2) { if (b) ok_i = 0; if (b != 0 && b != 0x80) ok_f = 0; }
    else             { if (b) ok_i = 0; if (b != 0 && b != 0x3f) ok_f = 0; }
  }
  int all_i = __syncthreads_and(ok_i);
  int all_f = __syncthreads_and(ok_f);
  if (tid == 0) meta[0] = all_i ? 0 : (all_f ? 1 : 2);
}

// histogram over (dst*4 + type) bins
__global__ void k_hist2(const int* __restrict__ dst, const int* __restrict__ typ,
                        int* __restrict__ hist, int n) {
  int i = blockIdx.x*256 + threadIdx.x;
  if (i < n) atomicAdd(&hist[dst[i]*4 + typ[i]], 1);
}

__global__ void k_hist(const int* __restrict__ key, int* __restrict__ hist, int n) {
  int i = blockIdx.x*256 + threadIdx.x;
  if (i < n) atomicAdd(&hist[key[i]], 1);
}

// exclusive scan, 2048 elems per block (8 per thread)
__global__ void k_scan1(const int* __restrict__ h, int* __restrict__ out,
                        int* __restrict__ bsum, int n) {
  __shared__ int sh[256];
  int t = threadIdx.x;
  int base = blockIdx.x*2048 + t*8;
  int v[8]; int s = 0;
  #pragma unroll
  for (int j = 0; j < 8; ++j) { v[j] = (base+j < n) ? h[base+j] : 0; s += v[j]; }
  sh[t] = s; __syncthreads();
  for (int off = 1; off < 256; off <<= 1) {
    int x = (t >= off) ? sh[t-off] : 0;
    __syncthreads();
    sh[t] += x;
    __syncthreads();
  }
  int ex = sh[t] - s;
  #pragma unroll
  for (int j = 0; j < 8; ++j) { if (base+j < n) out[base+j] = ex; ex += v[j]; }
  if (t == 255) bsum[blockIdx.x] = sh[255];
}

__global__ void k_scan2(int* __restrict__ b, int nb) {
  __shared__ int sh[256];
  int t = threadIdx.x;
  int s = (t < nb) ? b[t] : 0;
  sh[t] = s; __syncthreads();
  for (int off = 1; off < 256; off <<= 1) {
    int x = (t >= off) ? sh[t-off] : 0;
    __syncthreads();
    sh[t] += x;
    __syncthreads();
  }
  if (t < nb) b[t] = sh[t] - s;
}

__global__ void k_scan3(int* __restrict__ eoff, const int* __restrict__ bsum,
                        int* __restrict__ cursor, int n, int total) {
  int i = blockIdx.x*256 + threadIdx.x;
  if (i < n) {
    int v = eoff[i] + bsum[i >> 11];
    eoff[i] = v;
    cursor[i] = v;
  }
  if (i == 0) eoff[n] = total;
}

// scatter src into CSR-by-(dst,type) order
__global__ void k_scatter2(const int* __restrict__ src, const int* __restrict__ dst,
                           const int* __restrict__ typ, int* __restrict__ cursor,
                           int* __restrict__ out, int n) {
  int i = blockIdx.x*256 + threadIdx.x;
  if (i < n) {
    int key = dst[i]*4 + typ[i];
    int p = atomicAdd(&cursor[key], 1);
    out[p] = src[i];
  }
}

__global__ void k_scan_small(const int* __restrict__ gh, int* __restrict__ goff, int g) {
  __shared__ int sh[256];
  int t = threadIdx.x;
  int v[8]; int s = 0;
  #pragma unroll
  for (int j = 0; j < 8; ++j) { int idx = t*8+j; v[j] = (idx < g) ? gh[idx] : 0; s += v[j]; }
  sh[t] = s; __syncthreads();
  for (int off = 1; off < 256; off <<= 1) {
    int x = (t >= off) ? sh[t-off] : 0;
    __syncthreads();
    sh[t] += x;
    __syncthreads();
  }
  int ex = sh[t] - s;
  #pragma unroll
  for (int j = 0; j < 8; ++j) { int idx = t*8+j; if (idx < g) goff[idx] = ex; ex += v[j]; }
  if (t == 255) goff[g] = sh[255];
}

// pack W into MFMA B-fragment layout: Bp[((l*NKT+kt)*16+ct)*64+lane][j] =
//   B[k = kt*32 + (lane>>4)*8 + j][col = ct*16 + (lane&15)]
__global__ void k_pack_w(const float* __restrict__ Wrel, const float* __restrict__ Wself,
                         f16x8* __restrict__ Bp) {
  int id = blockIdx.x*256 + threadIdx.x;
  if (id >= L_*NKT*16*64) return;
  int lane = id & 63; int rest = id >> 6;
  int ct = rest & 15; rest >>= 4;
  int kt = rest % NKT; int l = rest / NKT;
  int q = lane >> 4, ln = lane & 15;
  int col = ct*16 + ln;
  f16x8 o;
  #pragma unroll
  for (int j = 0; j < 8; ++j) {
    int k = kt*32 + q*8 + j;
    float v = (k < R_*D_) ? Wrel[((size_t)l*R_*D_ + k)*D_ + col]
                          : Wself[((size_t)l*D_ + (k - R_*D_))*D_ + col];
    o[j] = (_Float16)v;
  }
  Bp[id] = o;
}

// x0 = node_feature + mask*flag_W[1] + flag_b  (f16); also copy node_feature to out cols [768:1024)
__global__ void k_node_init(const float* __restrict__ nf, const float* __restrict__ fW,
                            const float* __restrict__ fb, const void* __restrict__ cm,
                            const int* __restrict__ meta, _Float16* __restrict__ xa,
                            float* __restrict__ out) {
  int n = blockIdx.x, c = threadIdx.x;
  float v = nf[(size_t)n*D_ + c];
  out[(size_t)n*CTXW + 768 + c] = v;
  int mode = meta[0];
  bool mk;
  if (mode == 0)      mk = ((const int*)cm)[n] != 0;
  else if (mode == 1) mk = ((const float*)cm)[n] != 0.f;
  else                mk = ((const unsigned char*)cm)[n] != 0;
  float x0 = v + (mk ? fW[D_ + c] : 0.f) + fb[c];
  xa[(size_t)n*D_ + c] = (_Float16)x0;
}

// ---------- fused RGCN layer ----------
// block = 256 thr (4 waves), M-tile = 32 nodes (N_ % 32 == 0, no bounds checks).
// Gather: wave w owns rows [w*8, w*8+8); 8 lanes per row. Load instruction i covers
//   CONTIGUOUS bytes [i*128, i*128+128) of the 512B src row: lane kch reads
//   i*128 + kch*16 -> exactly 1 cache line per row-group per instruction (no dup).
// Accumulate 32 f32/lane in regs; CSR-by-(dst,type) -> exact per-relation segments.
// A staged to LDS as f16, XOR-swizzled granules (granule g stored at g^(row&7)),
// double-buffered -> 1 barrier/relation.
__global__ __launch_bounds__(256, 4)
void k_layer(const _Float16* __restrict__ xin, const f16x8* __restrict__ Bp,
             const float* __restrict__ bias, const int* __restrict__ eoff2,
             const int* __restrict__ es, float* __restrict__ outp,
             _Float16* __restrict__ xout) {
  __shared__ f16x8 As16[2][32*32];   // [buf][row*32 + swizzled granule], 32 KB
  const int tid = threadIdx.x;
  const int lane = tid & 63, wave = tid >> 6;
  const int q = lane >> 4, ln = lane & 15;
  const int m0 = blockIdx.x * 32;
  const int kch = lane & 7;              // 16B sub-chunk within 128B window
  const int row = wave*8 + (lane >> 3);  // 0..31
  const int nd  = m0 + row;

  int oo[5];
  #pragma unroll
  for (int j = 0; j < 5; ++j) oo[j] = eoff2[nd*4 + j];
  const int degt = oo[4] - oo[0];
  const float invd = 1.0f / (float)(degt > 1 ? degt : 1);

  f32x4 acc[2][4];
  #pragma unroll
  for (int rt = 0; rt < 2; ++rt)
    #pragma unroll
    for (int cc = 0; cc < 4; ++cc)
      acc[rt][cc] = f32x4{0.f,0.f,0.f,0.f};

  // ---- self phase: A = xin rows directly (k in [1024,1280)) ----
  {
    const _Float16* r0 = xin + (size_t)(m0 + ln)*D_;
    const _Float16* r1 = xin + (size_t)(m0 + 16 + ln)*D_;
    #pragma unroll
    for (int kt = 0; kt < 8; ++kt) {
      f16x8 a0 = *(const f16x8*)(r0 + kt*32 + q*8);
      f16x8 a1 = *(const f16x8*)(r1 + kt*32 + q*8);
      f16x8 b[4];
      #pragma unroll
      for (int cc = 0; cc < 4; ++cc)
        b[cc] = Bp[(size_t)((32 + kt)*16 + wave*4 + cc)*64 + lane];
      #pragma unroll
      for (int cc = 0; cc < 4; ++cc) {
        acc[0][cc] = __builtin_amdgcn_mfma_f32_16x16x32_f16(a0, b[cc], acc[0][cc], 0,0,0);
        acc[1][cc] = __builtin_amdgcn_mfma_f32_16x16x32_f16(a1, b[cc], acc[1][cc], 0,0,0);
      }
    }
  }

  // ---- relation phases ----
  #pragma unroll
  for (int r = 0; r < R_; ++r) {
    // register gather for (row, relation r); lane holds granules {i*8+kch : i=0..3}
    f32x4 ax[8];
    #pragma unroll
    for (int i = 0; i < 8; ++i) ax[i] = f32x4{0.f,0.f,0.f,0.f};
    for (int e = oo[r]; e < oo[r+1]; ++e) {
      int src = es[e];   // same for the 8 lanes of this row-group
      const f16x8* sp = (const f16x8*)(xin + (size_t)src*D_);
      f16x8 w0 = sp[0*8 + kch];   // contiguous 128B across the 8-lane group
      f16x8 w1 = sp[1*8 + kch];
      f16x8 w2 = sp[2*8 + kch];
      f16x8 w3 = sp[3*8 + kch];
      ax[0] += f32x4{(float)w0[0],(float)w0[1],(float)w0[2],(float)w0[3]};
      ax[1] += f32x4{(float)w0[4],(float)w0[5],(float)w0[6],(float)w0[7]};
      ax[2] += f32x4{(float)w1[0],(float)w1[1],(float)w1[2],(float)w1[3]};
      ax[3] += f32x4{(float)w1[4],(float)w1[5],(float)w1[6],(float)w1[7]};
      ax[4] += f32x4{(float)w2[0],(float)w2[1],(float)w2[2],(float)w2[3]};
      ax[5] += f32x4{(float)w2[4],(float)w2[5],(float)w2[6],(float)w2[7]};
      ax[6] += f32x4{(float)w3[0],(float)w3[1],(float)w3[2],(float)w3[3]};
      ax[7] += f32x4{(float)w3[4],(float)w3[5],(float)w3[6],(float)w3[7]};
    }
    // scale by 1/deg, convert to f16, write swizzled A tile (granule i*8+kch)
    f16x8* dstb = &As16[r & 1][row*32];
    #pragma unroll
    for (int i = 0; i < 4; ++i) {
      f32x4 lo = ax[2*i], hi = ax[2*i+1];
      f16x8 o;
      o[0] = (_Float16)(lo[0]*invd); o[1] = (_Float16)(lo[1]*invd);
      o[2] = (_Float16)(lo[2]*invd); o[3] = (_Float16)(lo[3]*invd);
      o[4] = (_Float16)(hi[0]*invd); o[5] = (_Float16)(hi[1]*invd);
      o[6] = (_Float16)(hi[2]*invd); o[7] = (_Float16)(hi[3]*invd);
      dstb[(i*8 + kch) ^ (row & 7)] = o;
    }
    __syncthreads();
    const f16x8* As = As16[r & 1];
    #pragma unroll
    for (int kt = 0; kt < 8; ++kt) {
      f16x8 a0 = As[(size_t)ln*32      + ((kt*4 + q) ^ (ln & 7))];
      f16x8 a1 = As[(size_t)(16+ln)*32 + ((kt*4 + q) ^ (ln & 7))];
      f16x8 b[4];
      #pragma unroll
      for (int cc = 0; cc < 4; ++cc)
        b[cc] = Bp[(size_t)((r*8 + kt)*16 + wave*4 + cc)*64 + lane];
      #pragma unroll
      for (int cc = 0; cc < 4; ++cc) {
        acc[0][cc] = __builtin_amdgcn_mfma_f32_16x16x32_f16(a0, b[cc], acc[0][cc], 0,0,0);
        acc[1][cc] = __builtin_amdgcn_mfma_f32_16x16x32_f16(a1, b[cc], acc[1][cc], 0,0,0);
      }
    }
    // next relation writes the other buffer; its barrier also fences these reads
  }

  // epilogue: +bias, relu, write strided fp32 to out, compact f16 to xout
  #pragma unroll
  for (int cc = 0; cc < 4; ++cc) {
    int col = (wave*4 + cc)*16 + ln;
    float bv = bias[col];
    #pragma unroll
    for (int rt = 0; rt < 2; ++rt) {
      #pragma unroll
      for (int i = 0; i < 4; ++i) {
        int rrow = m0 + rt*16 + q*4 + i;
        float v = acc[rt][cc][i] + bv;
        v = fmaxf(v, 0.f);
        outp[(size_t)rrow*CTXW + col] = v;
        if (xout) xout[(size_t)rrow*D_ + col] = (_Float16)v;
      }
    }
  }
}

// segment-mean over sorted batch + broadcast to member node rows; one block per graph
__global__ void k_pool(float* __restrict__ out, const int* __restrict__ goff,
                       const int* __restrict__ rxn) {
  int g = blockIdx.x, t = threadIdx.x;
  int s = goff[g], e = goff[g+1];
  int cnt = e - s;
  float inv = 1.0f / (float)(cnt > 1 ? cnt : 1);
  float a0 = 0.f, a1 = 0.f, a2 = 0.f;
  for (int nn = s; nn < e; ++nn) {
    size_t base = (size_t)nn*CTXW;
    a0 += out[base + t];
    a1 += out[base + 256 + t];
    a2 += out[base + 512 + t];
  }
  a0 *= inv; a1 *= inv; a2 *= inv;
  float rx = 0.f;
  int rv = rxn[g];
  size_t gbase = (size_t)N_*CTXW + (size_t)g*GCTXW;
  out[gbase + t]       = a0;
  out[gbase + 256 + t] = a1;
  out[gbase + 512 + t] = a2;
  if (t < NRXN_) { rx = (rv == t) ? 1.f : 0.f; out[gbase + 768 + t] = rx; }
  // broadcast graph context into member node rows (batch sorted -> contiguous)
  for (int nn = s; nn < e; ++nn) {
    size_t nb = (size_t)nn*CTXW + 1024;
    out[nb + t]       = a0;
    out[nb + 256 + t] = a1;
    out[nb + 512 + t] = a2;
    if (t < NRXN_) out[nb + 768 + t] = rx;
  }
}

extern "C" void kernel_launch(void* const* d_in, const int* in_sizes, int n_in,
                              void* d_out, int out_size, void* d_ws, size_t ws_size,
                              hipStream_t stream) {
  const float* node_feature = (const float*)d_in[0];
  const float* flag_W  = (const float*)d_in[1];
  const float* flag_b  = (const float*)d_in[2];
  const float* W_self  = (const float*)d_in[3];
  const float* b_self  = (const float*)d_in[4];
  const float* W_rel   = (const float*)d_in[5];
  const int* edge_src  = (const int*)d_in[6];
  const int* edge_dst  = (const int*)d_in[7];
  const int* edge_type = (const int*)d_in[8];
  const int* batch     = (const int*)d_in[9];
  const int* reaction  = (const int*)d_in[10];
  const void* cmask    = d_in[11];
  float* out = (float*)d_out;

  char* ws = (char*)d_ws;
  size_t off = 0;
  auto alloc = [&](size_t bytes) {
    void* p = ws + off;
    off = (off + bytes + 255) & ~(size_t)255;
    return p;
  };
  int* meta          = (int*)alloc(256);
  _Float16* xa       = (_Float16*)alloc((size_t)N_*D_*2);
  _Float16* xb       = (_Float16*)alloc((size_t)N_*D_*2);
  f16x8* Bp          = (f16x8*)alloc((size_t)L_*NKT*16*64*16);
  int* eoff2         = (int*)alloc((size_t)(NR+1)*4);
  int* cursor        = (int*)alloc((size_t)NR*4);
  int* ghist         = (int*)alloc((size_t)G_*4);
  int* goff          = (int*)alloc((size_t)(G_+1)*4);
  int* bsum          = (int*)alloc(1024);
  int* esorted       = (int*)alloc((size_t)E_*4);
  (void)in_sizes; (void)n_in; (void)out_size; (void)ws_size;

  k_detect<<<1, 256, 0, stream>>>((const unsigned char*)cmask, meta);
  k_zero<<<(NR+255)/256, 256, 0, stream>>>(cursor, NR);
  k_zero<<<(G_+255)/256, 256, 0, stream>>>(ghist, G_);
  k_hist2<<<(E_+255)/256, 256, 0, stream>>>(edge_dst, edge_type, cursor, E_);
  k_scan1<<<NB2, 256, 0, stream>>>(cursor, eoff2, bsum, NR);
  k_scan2<<<1, 256, 0, stream>>>(bsum, NB2);
  k_scan3<<<(NR+255)/256, 256, 0, stream>>>(eoff2, bsum, cursor, NR, E_);
  k_scatter2<<<(E_+255)/256, 256, 0, stream>>>(edge_src, edge_dst, edge_type, cursor, esorted, E_);
  k_hist<<<(N_+255)/256, 256, 0, stream>>>(batch, ghist, N_);
  k_scan_small<<<1, 256, 0, stream>>>(ghist, goff, G_);
  k_pack_w<<<(L_*NKT*16*64 + 255)/256, 256, 0, stream>>>(W_rel, W_self, Bp);
  k_node_init<<<N_, 256, 0, stream>>>(node_feature, flag_W, flag_b, cmask, meta, xa, out);

  const int nblk = N_ / 32;
  k_layer<<<nblk, 256, 0, stream>>>(xa, Bp,          b_self,       eoff2, esorted, out,       xb);
  k_layer<<<nblk, 256, 0, stream>>>(xb, Bp + 40960,  b_self + 256, eoff2, esorted, out + 256, xa);
  k_layer<<<nblk, 256, 0, stream>>>(xa, Bp + 81920,  b_self + 512, eoff2, esorted, out + 512, nullptr);

  k_pool<<<G_, 256, 0, stream>>>(out, goff, reaction);
}

// Round 3
// 1447.556 us; speedup vs baseline: 1.3778x; 1.0439x over previous
//
#include <hip/hip_runtime.h>
#include <hip/hip_bf16.h>

typedef _Float16 f16x8 __attribute__((ext_vector_type(8)));
typedef float f32x4 __attribute__((ext_vector_type(4)));

namespace {
constexpr int N_ = 100000;
constexpr int E_ = 400000;
constexpr int D_ = 256;
constexpr int L_ = 3;
constexpr int R_ = 4;
constexpr int G_ = 2000;
constexpr int NRXN_ = 10;
constexpr int CTXW = L_*D_ + D_ + L_*D_ + NRXN_;   // 1802
constexpr int GCTXW = L_*D_ + NRXN_;               // 778
constexpr int NKT = (R_+1)*D_/32;                  // 40 k-tiles of 32
constexpr int NR = N_*R_;                          // 400000 (dst,type) bins
constexpr int NB2 = (NR + 2047)/2048;              // 196 scan blocks
}

// ---------- small utility kernels ----------

__global__ void k_zero(int* __restrict__ p, int n) {
  int i = blockIdx.x*256 + threadIdx.x;
  if (i < n) p[i] = 0;
}

// sniff center_mask dtype: 0=int32, 1=float32, 2=byte(bool)
__global__ void k_detect(const unsigned char* __restrict__ cm, int* __restrict__ meta) {
  int tid = threadIdx.x;
  int ok_i = 1, ok_f = 1;
  for (int i = tid; i < 4096; i += 256) {
    unsigned b = cm[i];
    int m = i & 3;
    if (m == 0)      { if (b > 1) ok_i = 0; if (b != 0) ok_f = 0; }
    else if (m == 1) { if (b) { ok_i = 0; ok_f = 0; } }
    else if (m == 2) { if (b) ok_i = 0; if (b != 0 && b != 0x80) ok_f = 0; }
    else             { if (b) ok_i = 0; if (b != 0 && b != 0x3f) ok_f = 0; }
  }
  int all_i = __syncthreads_and(ok_i);
  int all_f = __syncthreads_and(ok_f);
  if (tid == 0) meta[0] = all_i ? 0 : (all_f ? 1 : 2);
}

// histogram over (dst*4 + type) bins
__global__ void k_hist2(const int* __restrict__ dst, const int* __restrict__ typ,
                        int* __restrict__ hist, int n) {
  int i = blockIdx.x*256 + threadIdx.x;
  if (i < n) atomicAdd(&hist[dst[i]*4 + typ[i]], 1);
}

__global__ void k_hist(const int* __restrict__ key, int* __restrict__ hist, int n) {
  int i = blockIdx.x*256 + threadIdx.x;
  if (i < n) atomicAdd(&hist[key[i]], 1);
}

// exclusive scan, 2048 elems per block (8 per thread)
__global__ void k_scan1(const int* __restrict__ h, int* __restrict__ out,
                        int* __restrict__ bsum, int n) {
  __shared__ int sh[256];
  int t = threadIdx.x;
  int base = blockIdx.x*2048 + t*8;
  int v[8]; int s = 0;
  #pragma unroll
  for (int j = 0; j < 8; ++j) { v[j] = (base+j < n) ? h[base+j] : 0; s += v[j]; }
  sh[t] = s; __syncthreads();
  for (int off = 1; off < 256; off <<= 1) {
    int x = (t >= off) ? sh[t-off] : 0;
    __syncthreads();
    sh[t] += x;
    __syncthreads();
  }
  int ex = sh[t] - s;
  #pragma unroll
  for (int j = 0; j < 8; ++j) { if (base+j < n) out[base+j] = ex; ex += v[j]; }
  if (t == 255) bsum[blockIdx.x] = sh[255];
}

__global__ void k_scan2(int* __restrict__ b, int nb) {
  __shared__ int sh[256];
  int t = threadIdx.x;
  int s = (t < nb) ? b[t] : 0;
  sh[t] = s; __syncthreads();
  for (int off = 1; off < 256; off <<= 1) {
    int x = (t >= off) ? sh[t-off] : 0;
    __syncthreads();
    sh[t] += x;
    __syncthreads();
  }
  if (t < nb) b[t] = sh[t] - s;
}

__global__ void k_scan3(int* __restrict__ eoff, const int* __restrict__ bsum,
                        int* __restrict__ cursor, int n, int total) {
  int i = blockIdx.x*256 + threadIdx.x;
  if (i < n) {
    int v = eoff[i] + bsum[i >> 11];
    eoff[i] = v;
    cursor[i] = v;
  }
  if (i == 0) eoff[n] = total;
}

// scatter src into CSR-by-(dst,type) order
__global__ void k_scatter2(const int* __restrict__ src, const int* __restrict__ dst,
                           const int* __restrict__ typ, int* __restrict__ cursor,
                           int* __restrict__ out, int n) {
  int i = blockIdx.x*256 + threadIdx.x;
  if (i < n) {
    int key = dst[i]*4 + typ[i];
    int p = atomicAdd(&cursor[key], 1);
    out[p] = src[i];
  }
}

__global__ void k_scan_small(const int* __restrict__ gh, int* __restrict__ goff, int g) {
  __shared__ int sh[256];
  int t = threadIdx.x;
  int v[8]; int s = 0;
  #pragma unroll
  for (int j = 0; j < 8; ++j) { int idx = t*8+j; v[j] = (idx < g) ? gh[idx] : 0; s += v[j]; }
  sh[t] = s; __syncthreads();
  for (int off = 1; off < 256; off <<= 1) {
    int x = (t >= off) ? sh[t-off] : 0;
    __syncthreads();
    sh[t] += x;
    __syncthreads();
  }
  int ex = sh[t] - s;
  #pragma unroll
  for (int j = 0; j < 8; ++j) { int idx = t*8+j; if (idx < g) goff[idx] = ex; ex += v[j]; }
  if (t == 255) goff[g] = sh[255];
}

// pack W into MFMA B-fragment layout: Bp[((l*NKT+kt)*16+ct)*64+lane][j] =
//   B[k = kt*32 + (lane>>4)*8 + j][col = ct*16 + (lane&15)]
__global__ void k_pack_w(const float* __restrict__ Wrel, const float* __restrict__ Wself,
                         f16x8* __restrict__ Bp) {
  int id = blockIdx.x*256 + threadIdx.x;
  if (id >= L_*NKT*16*64) return;
  int lane = id & 63; int rest = id >> 6;
  int ct = rest & 15; rest >>= 4;
  int kt = rest % NKT; int l = rest / NKT;
  int q = lane >> 4, ln = lane & 15;
  int col = ct*16 + ln;
  f16x8 o;
  #pragma unroll
  for (int j = 0; j < 8; ++j) {
    int k = kt*32 + q*8 + j;
    float v = (k < R_*D_) ? Wrel[((size_t)l*R_*D_ + k)*D_ + col]
                          : Wself[((size_t)l*D_ + (k - R_*D_))*D_ + col];
    o[j] = (_Float16)v;
  }
  Bp[id] = o;
}

// x0 = node_feature + mask*flag_W[1] + flag_b (f16); copy node_feature to out cols [768:1024)
// vectorized: 8 nodes/block, thread t -> node blk*8 + t/32, 8-float chunk (t%32)*8
__global__ void k_node_init(const float* __restrict__ nf, const float* __restrict__ fW,
                            const float* __restrict__ fb, const void* __restrict__ cm,
                            const int* __restrict__ meta, _Float16* __restrict__ xa,
                            float* __restrict__ out) {
  int t = threadIdx.x;
  int n = blockIdx.x*8 + (t >> 5);
  int c = (t & 31)*8;
  const f32x4* nf4 = (const f32x4*)(nf + (size_t)n*D_ + c);
  f32x4 v0 = nf4[0], v1 = nf4[1];
  float* ob = out + (size_t)n*CTXW + 768 + c;
  *(f32x4*)ob = v0;
  *(f32x4*)(ob + 4) = v1;
  int mode = meta[0];
  bool mk;
  if (mode == 0)      mk = ((const int*)cm)[n] != 0;
  else if (mode == 1) mk = ((const float*)cm)[n] != 0.f;
  else                mk = ((const unsigned char*)cm)[n] != 0;
  float m = mk ? 1.f : 0.f;
  f32x4 w0 = *(const f32x4*)(fW + D_ + c);
  f32x4 w1 = *(const f32x4*)(fW + D_ + c + 4);
  f32x4 b0 = *(const f32x4*)(fb + c);
  f32x4 b1 = *(const f32x4*)(fb + c + 4);
  f32x4 x0 = v0 + w0*m + b0;
  f32x4 x1 = v1 + w1*m + b1;
  f16x8 o;
  o[0]=(_Float16)x0[0]; o[1]=(_Float16)x0[1]; o[2]=(_Float16)x0[2]; o[3]=(_Float16)x0[3];
  o[4]=(_Float16)x1[0]; o[5]=(_Float16)x1[1]; o[6]=(_Float16)x1[2]; o[7]=(_Float16)x1[3];
  *(f16x8*)(xa + (size_t)n*D_ + c) = o;
}

// ---------- fused RGCN layer ----------
// block = 256 thr (4 waves), M-tile = 32 nodes (N_ % 32 == 0, no bounds checks).
// Gather: wave w owns rows [w*8, w*8+8); 8 lanes per row; lane kch reads the 16B at
//   i*128 + kch*16 (contiguous 128B window per instr; 1 line per row-group per instr).
// DEPTH-2 SOFTWARE PIPELINE: next edge's index + 4 row loads issue before the current
//   edge's accumulate -> per-iteration chains are independent (latency hidden by ILP).
// MFMA loops register-double-buffer the 4 B-fragments (kt+1 loads during kt's MFMAs).
// A staged to LDS f16, XOR-swizzled granules, double-buffered -> 1 barrier/relation.
__global__ __launch_bounds__(256, 4)
void k_layer(const _Float16* __restrict__ xin, const f16x8* __restrict__ Bp,
             const float* __restrict__ bias, const int* __restrict__ eoff2,
             const int* __restrict__ es, float* __restrict__ outp,
             _Float16* __restrict__ xout) {
  __shared__ f16x8 As16[2][32*32];   // [buf][row*32 + swizzled granule], 32 KB
  const int tid = threadIdx.x;
  const int lane = tid & 63, wave = tid >> 6;
  const int q = lane >> 4, ln = lane & 15;
  const int m0 = blockIdx.x * 32;
  const int kch = lane & 7;              // 16B sub-chunk within 128B window
  const int row = wave*8 + (lane >> 3);  // 0..31
  const int nd  = m0 + row;

  int oo[5];
  #pragma unroll
  for (int j = 0; j < 5; ++j) oo[j] = eoff2[nd*4 + j];
  const int degt = oo[4] - oo[0];
  const float invd = 1.0f / (float)(degt > 1 ? degt : 1);

  f32x4 acc[2][4];
  #pragma unroll
  for (int rt = 0; rt < 2; ++rt)
    #pragma unroll
    for (int cc = 0; cc < 4; ++cc)
      acc[rt][cc] = f32x4{0.f,0.f,0.f,0.f};

  // ---- self phase: A = xin rows directly (k in [1024,1280)) ----
  {
    const _Float16* r0 = xin + (size_t)(m0 + ln)*D_;
    const _Float16* r1 = r0 + (size_t)16*D_;
    const f16x8* bb = Bp + ((size_t)(32*16 + wave*4))*64 + lane;  // elem (kt,cc) at kt*1024+cc*64
    f16x8 bc[4];
    #pragma unroll
    for (int cc = 0; cc < 4; ++cc) bc[cc] = bb[cc*64];
    #pragma unroll
    for (int kt = 0; kt < 8; ++kt) {
      f16x8 a0 = *(const f16x8*)(r0 + kt*32 + q*8);
      f16x8 a1 = *(const f16x8*)(r1 + kt*32 + q*8);
      f16x8 bn[4];
      if (kt < 7) {
        #pragma unroll
        for (int cc = 0; cc < 4; ++cc) bn[cc] = bb[(kt+1)*1024 + cc*64];
      }
      #pragma unroll
      for (int cc = 0; cc < 4; ++cc) {
        acc[0][cc] = __builtin_amdgcn_mfma_f32_16x16x32_f16(a0, bc[cc], acc[0][cc], 0,0,0);
        acc[1][cc] = __builtin_amdgcn_mfma_f32_16x16x32_f16(a1, bc[cc], acc[1][cc], 0,0,0);
      }
      if (kt < 7) {
        #pragma unroll
        for (int cc = 0; cc < 4; ++cc) bc[cc] = bn[cc];
      }
    }
  }

  // ---- relation phases ----
  #pragma unroll
  for (int r = 0; r < R_; ++r) {
    f32x4 ax[8];
    #pragma unroll
    for (int i = 0; i < 8; ++i) ax[i] = f32x4{0.f,0.f,0.f,0.f};

    auto accum = [&](f16x8 w0, f16x8 w1, f16x8 w2, f16x8 w3) {
      ax[0] += f32x4{(float)w0[0],(float)w0[1],(float)w0[2],(float)w0[3]};
      ax[1] += f32x4{(float)w0[4],(float)w0[5],(float)w0[6],(float)w0[7]};
      ax[2] += f32x4{(float)w1[0],(float)w1[1],(float)w1[2],(float)w1[3]};
      ax[3] += f32x4{(float)w1[4],(float)w1[5],(float)w1[6],(float)w1[7]};
      ax[4] += f32x4{(float)w2[0],(float)w2[1],(float)w2[2],(float)w2[3]};
      ax[5] += f32x4{(float)w2[4],(float)w2[5],(float)w2[6],(float)w2[7]};
      ax[6] += f32x4{(float)w3[0],(float)w3[1],(float)w3[2],(float)w3[3]};
      ax[7] += f32x4{(float)w3[4],(float)w3[5],(float)w3[6],(float)w3[7]};
    };

    {
      int e0 = oo[r], e1 = oo[r+1];
      if (e0 < e1) {
        const f16x8* sp = (const f16x8*)(xin + (size_t)es[e0]*D_);
        f16x8 w0 = sp[kch], w1 = sp[8+kch], w2 = sp[16+kch], w3 = sp[24+kch];
        for (int e = e0 + 1; e < e1; ++e) {
          const f16x8* sn = (const f16x8*)(xin + (size_t)es[e]*D_);  // independent of w*
          f16x8 n0 = sn[kch], n1 = sn[8+kch], n2 = sn[16+kch], n3 = sn[24+kch];
          accum(w0, w1, w2, w3);
          w0 = n0; w1 = n1; w2 = n2; w3 = n3;
        }
        accum(w0, w1, w2, w3);
      }
    }

    // scale by 1/deg, convert to f16, write swizzled A tile (granule i*8+kch)
    f16x8* dstb = &As16[r & 1][row*32];
    #pragma unroll
    for (int i = 0; i < 4; ++i) {
      f32x4 lo = ax[2*i], hi = ax[2*i+1];
      f16x8 o;
      o[0] = (_Float16)(lo[0]*invd); o[1] = (_Float16)(lo[1]*invd);
      o[2] = (_Float16)(lo[2]*invd); o[3] = (_Float16)(lo[3]*invd);
      o[4] = (_Float16)(hi[0]*invd); o[5] = (_Float16)(hi[1]*invd);
      o[6] = (_Float16)(hi[2]*invd); o[7] = (_Float16)(hi[3]*invd);
      dstb[(i*8 + kch) ^ (row & 7)] = o;
    }
    __syncthreads();
    const f16x8* As = As16[r & 1];
    const f16x8* bb = Bp + ((size_t)(r*8*16 + wave*4))*64 + lane;  // elem (kt,cc) at kt*1024+cc*64
    f16x8 bc[4];
    #pragma unroll
    for (int cc = 0; cc < 4; ++cc) bc[cc] = bb[cc*64];
    #pragma unroll
    for (int kt = 0; kt < 8; ++kt) {
      f16x8 a0 = As[(size_t)ln*32      + ((kt*4 + q) ^ (ln & 7))];
      f16x8 a1 = As[(size_t)(16+ln)*32 + ((kt*4 + q) ^ (ln & 7))];
      f16x8 bn[4];
      if (kt < 7) {
        #pragma unroll
        for (int cc = 0; cc < 4; ++cc) bn[cc] = bb[(kt+1)*1024 + cc*64];
      }
      #pragma unroll
      for (int cc = 0; cc < 4; ++cc) {
        acc[0][cc] = __builtin_amdgcn_mfma_f32_16x16x32_f16(a0, bc[cc], acc[0][cc], 0,0,0);
        acc[1][cc] = __builtin_amdgcn_mfma_f32_16x16x32_f16(a1, bc[cc], acc[1][cc], 0,0,0);
      }
      if (kt < 7) {
        #pragma unroll
        for (int cc = 0; cc < 4; ++cc) bc[cc] = bn[cc];
      }
    }
    // next relation writes the other buffer; its barrier also fences these reads
  }

  // epilogue: +bias, relu, write strided fp32 to out, compact f16 to xout
  #pragma unroll
  for (int cc = 0; cc < 4; ++cc) {
    int col = (wave*4 + cc)*16 + ln;
    float bv = bias[col];
    #pragma unroll
    for (int rt = 0; rt < 2; ++rt) {
      #pragma unroll
      for (int i = 0; i < 4; ++i) {
        int rrow = m0 + rt*16 + q*4 + i;
        float v = acc[rt][cc][i] + bv;
        v = fmaxf(v, 0.f);
        outp[(size_t)rrow*CTXW + col] = v;
        if (xout) xout[(size_t)rrow*D_ + col] = (_Float16)v;
      }
    }
  }
}

// segment-mean over sorted batch + broadcast to member node rows; one block per graph.
// f32x4 per thread (threads 0..191 cover 768 cols), 2-way unrolled accumulate.
__global__ void k_pool(float* __restrict__ out, const int* __restrict__ goff,
                       const int* __restrict__ rxn) {
  int g = blockIdx.x, t = threadIdx.x;
  int s = goff[g], e = goff[g+1];
  int cnt = e - s;
  float inv = 1.0f / (float)(cnt > 1 ? cnt : 1);
  size_t gbase = (size_t)N_*CTXW + (size_t)g*GCTXW;
  if (t < 192) {
    int c = t*4;
    f32x4 a{0.f,0.f,0.f,0.f}, b{0.f,0.f,0.f,0.f};
    int nn = s;
    for (; nn + 1 < e; nn += 2) {
      f32x4 p = *(const f32x4*)(out + (size_t)nn*CTXW + c);
      f32x4 q2 = *(const f32x4*)(out + (size_t)(nn+1)*CTXW + c);
      a += p; b += q2;
    }
    if (nn < e) a += *(const f32x4*)(out + (size_t)nn*CTXW + c);
    a += b;
    a = a * inv;
    *(f32x4*)(out + gbase + c) = a;
    for (int nn2 = s; nn2 < e; ++nn2)
      *(f32x4*)(out + (size_t)nn2*CTXW + 1024 + c) = a;
  } else if (t < 192 + NRXN_) {
    int k = t - 192;
    float rv = (rxn[g] == k) ? 1.f : 0.f;
    out[gbase + 768 + k] = rv;
    for (int nn2 = s; nn2 < e; ++nn2)
      out[(size_t)nn2*CTXW + 1024 + 768 + k] = rv;
  }
}

extern "C" void kernel_launch(void* const* d_in, const int* in_sizes, int n_in,
                              void* d_out, int out_size, void* d_ws, size_t ws_size,
                              hipStream_t stream) {
  const float* node_feature = (const float*)d_in[0];
  const float* flag_W  = (const float*)d_in[1];
  const float* flag_b  = (const float*)d_in[2];
  const float* W_self  = (const float*)d_in[3];
  const float* b_self  = (const float*)d_in[4];
  const float* W_rel   = (const float*)d_in[5];
  const int* edge_src  = (const int*)d_in[6];
  const int* edge_dst  = (const int*)d_in[7];
  const int* edge_type = (const int*)d_in[8];
  const int* batch     = (const int*)d_in[9];
  const int* reaction  = (const int*)d_in[10];
  const void* cmask    = d_in[11];
  float* out = (float*)d_out;

  char* ws = (char*)d_ws;
  size_t off = 0;
  auto alloc = [&](size_t bytes) {
    void* p = ws + off;
    off = (off + bytes + 255) & ~(size_t)255;
    return p;
  };
  int* meta          = (int*)alloc(256);
  _Float16* xa       = (_Float16*)alloc((size_t)N_*D_*2);
  _Float16* xb       = (_Float16*)alloc((size_t)N_*D_*2);
  f16x8* Bp          = (f16x8*)alloc((size_t)L_*NKT*16*64*16);
  int* eoff2         = (int*)alloc((size_t)(NR+1)*4);
  int* cursor        = (int*)alloc((size_t)NR*4);
  int* ghist         = (int*)alloc((size_t)G_*4);
  int* goff          = (int*)alloc((size_t)(G_+1)*4);
  int* bsum          = (int*)alloc(1024);
  int* esorted       = (int*)alloc((size_t)E_*4);
  (void)in_sizes; (void)n_in; (void)out_size; (void)ws_size;

  k_detect<<<1, 256, 0, stream>>>((const unsigned char*)cmask, meta);
  k_zero<<<(NR+255)/256, 256, 0, stream>>>(cursor, NR);
  k_zero<<<(G_+255)/256, 256, 0, stream>>>(ghist, G_);
  k_hist2<<<(E_+255)/256, 256, 0, stream>>>(edge_dst, edge_type, cursor, E_);
  k_scan1<<<NB2, 256, 0, stream>>>(cursor, eoff2, bsum, NR);
  k_scan2<<<1, 256, 0, stream>>>(bsum, NB2);
  k_scan3<<<(NR+255)/256, 256, 0, stream>>>(eoff2, bsum, cursor, NR, E_);
  k_scatter2<<<(E_+255)/256, 256, 0, stream>>>(edge_src, edge_dst, edge_type, cursor, esorted, E_);
  k_hist<<<(N_+255)/256, 256, 0, stream>>>(batch, ghist, N_);
  k_scan_small<<<1, 256, 0, stream>>>(ghist, goff, G_);
  k_pack_w<<<(L_*NKT*16*64 + 255)/256, 256, 0, stream>>>(W_rel, W_self, Bp);
  k_node_init<<<N_/8, 256, 0, stream>>>(node_feature, flag_W, flag_b, cmask, meta, xa, out);

  const int nblk = N_ / 32;
  k_layer<<<nblk, 256, 0, stream>>>(xa, Bp,          b_self,       eoff2, esorted, out,       xb);
  k_layer<<<nblk, 256, 0, stream>>>(xb, Bp + 40960,  b_self + 256, eoff2, esorted, out + 256, xa);
  k_layer<<<nblk, 256, 0, stream>>>(xa, Bp + 81920,  b_self + 512, eoff2, esorted, out + 512, nullptr);

  k_pool<<<G_, 256, 0, stream>>>(out, goff, reaction);
}